// Round 2
// baseline (170.150 us; speedup 1.0000x reference)
//
#include <hip/hip_runtime.h>

typedef unsigned long long ull;

// Problem constants (from reference)
#define N_BUSES     2000
#define BATCH       32
#define EDGES_PER_B 6000
#define TOTAL_BUSES (BATCH * N_BUSES)     // 64000
#define TOTAL_EDGES (BATCH * EDGES_PER_B) // 192000

// Single-array hash: slot = ((key+1) << 18) | edge_id, 0 = empty.
// key = (b*N+i)*N+j < 2^27; edge_id < 192000 < 2^18.
#define HBITS 18
#define HSIZE (1 << HBITS)   // 262144 slots, load factor 0.73
#define HMASK (HSIZE - 1)

// Workspace layout (bytes)
#define OFF_ACC    0                       // 5 doubles (d1re,d1im,d2,d3,mse)
#define OFF_TICKET 64                      // 1 uint
#define OFF_BSTATS 128                     // 3*BATCH floats
#define OFF_YV     512                     // 2*TOTAL_BUSES floats
#define OFF_SLOTS  (OFF_YV + 2 * TOTAL_BUSES * 4)  // HSIZE u64 (8-aligned: 512512/8 ok)
// total ~2.6 MB

__device__ __forceinline__ unsigned hash_key(int key) {
    return ((unsigned)key * 2654435761u) >> (32 - HBITS);
}

// Kernel 1: zero hash slots / yv / acc / ticket; blocks 0..31 also compute
// per-batch means of S (complex) and Vm (consumed only on exact zeros).
__global__ void init_and_stats(ull* __restrict__ slots, float* __restrict__ yv,
                               double* __restrict__ acc, unsigned* __restrict__ ticket,
                               const float* __restrict__ x, float* __restrict__ bstats) {
    int i = blockIdx.x * blockDim.x + threadIdx.x;   // grid covers HSIZE exactly
    slots[i] = 0ULL;
    if (i < 2 * TOTAL_BUSES) yv[i] = 0.0f;
    if (i < 8) acc[i] = 0.0;
    if (i == 8) *ticket = 0u;

    if (blockIdx.x < BATCH) {                        // uniform per block
        int b = blockIdx.x;
        int tid = threadIdx.x;
        double sre = 0.0, sim = 0.0, vm = 0.0;
        for (int k = tid; k < N_BUSES; k += blockDim.x) {
            const float* row = x + (size_t)(b * N_BUSES + k) * 6;
            sre += (double)row[0];
            sim += (double)row[1];
            vm  += (double)row[2];
        }
        for (int off = 32; off > 0; off >>= 1) {
            sre += __shfl_down(sre, off, 64);
            sim += __shfl_down(sim, off, 64);
            vm  += __shfl_down(vm,  off, 64);
        }
        __shared__ double sh[3][4];
        int wave = tid >> 6, lane = tid & 63;
        if (lane == 0) { sh[0][wave] = sre; sh[1][wave] = sim; sh[2][wave] = vm; }
        __syncthreads();
        if (tid == 0) {
            double a = 0, c = 0, d = 0;
            for (int w = 0; w < 4; w++) { a += sh[0][w]; c += sh[1][w]; d += sh[2][w]; }
            bstats[b]             = (float)(a / N_BUSES);
            bstats[BATCH + b]     = (float)(c / N_BUSES);
            bstats[2 * BATCH + b] = (float)(d / N_BUSES);
        }
    }
}

// Kernel 2: single-pass insert with last-write-wins resolution.
// numpy fancy-assign semantics: winner per (b,i,j) = highest flat edge index,
// which is exactly max of packed values sharing the key's high bits.
__global__ void edge_insert(const int* __restrict__ ei, ull* __restrict__ slots) {
    int m = blockIdx.x * blockDim.x + threadIdx.x;   // grid covers TOTAL_EDGES exactly
    int b = m / EDGES_PER_B;
    int i = ei[m] % N_BUSES;
    int j = ei[TOTAL_EDGES + m] % N_BUSES;
    int key = (b * N_BUSES + i) * N_BUSES + j;
    ull tag = (ull)(unsigned)(key + 1) << 18;
    ull packed = tag | (unsigned)m;
    unsigned h = hash_key(key);
    while (true) {
        ull old = atomicCAS(&slots[h], 0ULL, packed);
        if (old == 0ULL) break;
        if ((old & ~0x3FFFFULL) == tag) { atomicMax(&slots[h], packed); break; }
        h = (h + 1) & HMASK;
    }
}

// Kernel 3: winning edge per key contributes YV[b,i] += adm * V[b,j].
__global__ void edge_accum(const int* __restrict__ ei, const float* __restrict__ ea,
                           const float* __restrict__ outputs,
                           const ull* __restrict__ slots, float* __restrict__ yv) {
    int m = blockIdx.x * blockDim.x + threadIdx.x;
    int b = m / EDGES_PER_B;
    int i = ei[m] % N_BUSES;
    int j = ei[TOTAL_EDGES + m] % N_BUSES;
    int key = (b * N_BUSES + i) * N_BUSES + j;
    ull tag = (ull)(unsigned)(key + 1) << 18;
    unsigned h = hash_key(key);
    ull s;
    while (((s = slots[h]) & ~0x3FFFFULL) != tag) h = (h + 1) & HMASK;
    if ((int)(s & 0x3FFFFULL) != m) return;          // a later duplicate overwrote this edge
    float2 a = ((const float2*)ea)[m];
    float2 v = ((const float2*)outputs)[b * N_BUSES + j];
    int ti = (b * N_BUSES + i) * 2;
    atomicAdd(&yv[ti],     a.x * v.x - a.y * v.y);
    atomicAdd(&yv[ti + 1], a.x * v.y + a.y * v.x);
}

// Kernel 4: per-bus loss terms, block reduce, global atomic acc, last block finalizes.
__global__ void loss_finalize(const float* __restrict__ x, const float* __restrict__ outputs,
                              const float* __restrict__ labels, const float* __restrict__ yv,
                              const float* __restrict__ bstats, double* __restrict__ acc,
                              unsigned* __restrict__ ticket, float* __restrict__ out,
                              int out_size) {
    int idx = blockIdx.x * blockDim.x + threadIdx.x;  // grid covers TOTAL_BUSES exactly
    int b = idx / N_BUSES;
    const float2* row2 = (const float2*)(x + (size_t)idx * 6);
    float2 r0 = row2[0], r1 = row2[1], r2 = row2[2];
    float sre = r0.x, sim = r0.y, Vm = r1.x;
    float bt0 = r1.y, bt1 = r2.x, bt2 = r2.y;
    float2 v = ((const float2*)outputs)[idx];
    float2 yvv = ((const float2*)yv)[idx];
    // Spred = V * conj(YV)
    float spr = v.x * yvv.x + v.y * yvv.y;
    float spi = v.y * yvv.x - v.x * yvv.y;
    // |1/S| with zero fallback to 1/S_mean
    float ir, ii;
    if (sre != 0.0f || sim != 0.0f) {
        float den = sre * sre + sim * sim;
        ir = sre / den; ii = -sim / den;
    } else {
        float mr = bstats[b], mi = bstats[BATCH + b];
        float den = mr * mr + mi * mi;
        ir = mr / den; ii = -mi / den;
    }
    float sinv_norm = sqrtf(ir * ir + ii * ii);
    float cr = spr - sre, ci = spi - sim;
    float t_d1re = sinv_norm * ((cr * cr - ci * ci) * bt0 + (cr * cr) * bt1);
    float t_d1im = sinv_norm * (2.0f * cr * ci * bt0);
    float vminv = (Vm != 0.0f) ? (1.0f / Vm) : (1.0f / bstats[2 * BATCH + b]);
    float vmag = sqrtf(v.x * v.x + v.y * v.y);
    float t_d2 = fabsf(vmag * (bt1 + bt2) - Vm) * vminv;
    float t_d3 = fabsf(v.y * bt2) * vminv;
    float2 l = ((const float2*)labels)[idx];
    float e0 = v.x - l.x, e1 = v.y - l.y;
    float t_mse = e0 * e0 + e1 * e1;

    double v0 = t_d1re, v1 = t_d1im, v2 = t_d2, v3 = t_d3, v4 = t_mse;
    for (int off = 32; off > 0; off >>= 1) {
        v0 += __shfl_down(v0, off, 64);
        v1 += __shfl_down(v1, off, 64);
        v2 += __shfl_down(v2, off, 64);
        v3 += __shfl_down(v3, off, 64);
        v4 += __shfl_down(v4, off, 64);
    }
    __shared__ double sh[5][4];
    int tid = threadIdx.x;
    int wave = tid >> 6, lane = tid & 63;
    if (lane == 0) {
        sh[0][wave] = v0; sh[1][wave] = v1; sh[2][wave] = v2;
        sh[3][wave] = v3; sh[4][wave] = v4;
    }
    __syncthreads();
    if (tid == 0) {
        double a0 = 0, a1 = 0, a2 = 0, a3 = 0, a4 = 0;
        for (int w = 0; w < 4; w++) {
            a0 += sh[0][w]; a1 += sh[1][w]; a2 += sh[2][w];
            a3 += sh[3][w]; a4 += sh[4][w];
        }
        atomicAdd(&acc[0], a0); atomicAdd(&acc[1], a1); atomicAdd(&acc[2], a2);
        atomicAdd(&acc[3], a3); atomicAdd(&acc[4], a4);
        __threadfence();
        unsigned t = atomicAdd(ticket, 1u);
        if (t == gridDim.x - 1) {
            // last block: all acc atomics globally visible; read via RMW for
            // cross-XCD freshness.
            double d1re = atomicAdd(&acc[0], 0.0);
            double d1im = atomicAdd(&acc[1], 0.0);
            double d2   = atomicAdd(&acc[2], 0.0);
            double d3   = atomicAdd(&acc[3], 0.0);
            double msea = atomicAdd(&acc[4], 0.0);
            double inv = 1.0 / (double)TOTAL_BUSES;
            d1re *= inv; d1im *= inv; d2 *= inv; d3 *= inv;
            double mse = msea / (2.0 * (double)TOTAL_BUSES);
            double phre = d1re + d2 + d3, phim = d1im;
            double lre = mse + 0.1 * phre, lim = 0.1 * phim;
            if (out_size == 8) {
                out[0] = (float)lre;  out[1] = (float)lim;
                out[2] = (float)phre; out[3] = (float)phim;
                out[4] = (float)d1re; out[5] = (float)d1im;
                out[6] = (float)d2;   out[7] = (float)d3;
            } else {
                float vals[5] = {(float)lre, (float)phre, (float)d1re, (float)d2, (float)d3};
                int n = out_size < 5 ? out_size : 5;
                for (int k = 0; k < n; k++) out[k] = vals[k];
                for (int k = 5; k < out_size && k < 64; k++) out[k] = 0.0f;
            }
        }
    }
}

extern "C" void kernel_launch(void* const* d_in, const int* in_sizes, int n_in,
                              void* d_out, int out_size, void* d_ws, size_t ws_size,
                              hipStream_t stream) {
    const float* x       = (const float*)d_in[0];
    const float* ea      = (const float*)d_in[1];
    const int*   ei      = (const int*)d_in[2];
    const float* outputs = (const float*)d_in[3];
    const float* labels  = (const float*)d_in[4];

    char* ws = (char*)d_ws;
    double*   acc    = (double*)(ws + OFF_ACC);
    unsigned* ticket = (unsigned*)(ws + OFF_TICKET);
    float*    bstats = (float*)(ws + OFF_BSTATS);
    float*    yv     = (float*)(ws + OFF_YV);
    ull*      slots  = (ull*)(ws + OFF_SLOTS);

    init_and_stats<<<HSIZE / 256, 256, 0, stream>>>(slots, yv, acc, ticket, x, bstats);
    edge_insert<<<TOTAL_EDGES / 256, 256, 0, stream>>>(ei, slots);
    edge_accum<<<TOTAL_EDGES / 256, 256, 0, stream>>>(ei, ea, outputs, slots, yv);
    loss_finalize<<<TOTAL_BUSES / 256, 256, 0, stream>>>(x, outputs, labels, yv, bstats,
                                                         acc, ticket, (float*)d_out, out_size);
}

// Round 3
// 137.341 us; speedup vs baseline: 1.2389x; 1.2389x over previous
//
#include <hip/hip_runtime.h>

typedef unsigned long long ull;

// Problem constants (from reference)
#define N_BUSES     2000
#define BATCH       32
#define EDGES_PER_B 6000
#define TOTAL_BUSES (BATCH * N_BUSES)     // 64000
#define TOTAL_EDGES (BATCH * EDGES_PER_B) // 192000

// Per-image LDS hash: slot = ((key+1) << 13) | local_edge_id, 0 = empty.
// key = i*N_BUSES + j < 4e6 < 2^22; local edge id < 6000 < 2^13. packed < 2^35.
#define HBITS 13
#define HSIZE (1 << HBITS)   // 8192 slots for <=6000 distinct keys
#define HMASK (HSIZE - 1)

#define NTHREADS 1024

// Workspace: 32 blocks x 5 doubles of partial sums (d1re, d1im, d2, d3, mse)
// Written non-atomically by each block; summed by the finalize kernel
// (kernel-boundary ordering guarantees visibility — no fences/tickets needed).

__device__ __forceinline__ unsigned hash_key(int key) {
    return ((unsigned)key * 2654435761u) >> (32 - HBITS);
}

__global__ __launch_bounds__(NTHREADS, 1)
void fused_image(const float* __restrict__ x, const float* __restrict__ ea,
                 const int* __restrict__ ei, const float* __restrict__ outputs,
                 const float* __restrict__ labels, double* __restrict__ part) {
    __shared__ ull slots[HSIZE];            // 64 KB
    __shared__ float yv_sh[2 * N_BUSES];    // 16 KB
    __shared__ double red[5][NTHREADS / 64];
    __shared__ float bst[3];                // S_mean re/im, Vm_mean

    const int b = blockIdx.x;
    const int tid = threadIdx.x;
    const int wave = tid >> 6, lane = tid & 63;

    // ---- Phase 0: zero LDS ----
    for (int k = tid; k < HSIZE; k += NTHREADS) slots[k] = 0ULL;
    for (int k = tid; k < 2 * N_BUSES; k += NTHREADS) yv_sh[k] = 0.0f;

    // ---- Phase 1: per-image means of S (complex) and Vm ----
    {
        double sre = 0.0, sim = 0.0, svm = 0.0;
        for (int i = tid; i < N_BUSES; i += NTHREADS) {
            const float* row = x + (size_t)(b * N_BUSES + i) * 6;
            sre += (double)row[0];
            sim += (double)row[1];
            svm += (double)row[2];
        }
        for (int off = 32; off > 0; off >>= 1) {
            sre += __shfl_down(sre, off, 64);
            sim += __shfl_down(sim, off, 64);
            svm += __shfl_down(svm, off, 64);
        }
        if (lane == 0) { red[0][wave] = sre; red[1][wave] = sim; red[2][wave] = svm; }
        __syncthreads();   // also covers phase-0 LDS zeroing
        if (tid == 0) {
            double a = 0, c = 0, d = 0;
            for (int w = 0; w < NTHREADS / 64; w++) { a += red[0][w]; c += red[1][w]; d += red[2][w]; }
            bst[0] = (float)(a / N_BUSES);
            bst[1] = (float)(c / N_BUSES);
            bst[2] = (float)(d / N_BUSES);
        }
        __syncthreads();
    }

    // ---- Phase 2: edge insert with last-write-wins dedup (LDS hash) ----
    // numpy fancy-assign: last write per (i,j) wins = max local edge id.
    for (int e = tid; e < EDGES_PER_B; e += NTHREADS) {
        int m = b * EDGES_PER_B + e;
        int i = ei[m] % N_BUSES;
        int j = ei[TOTAL_EDGES + m] % N_BUSES;
        int key = i * N_BUSES + j;
        ull tag = (ull)(unsigned)(key + 1) << 13;
        ull packed = tag | (unsigned)e;
        unsigned h = hash_key(key);
        while (true) {
            ull old = atomicCAS(&slots[h], 0ULL, packed);
            if (old == 0ULL) break;
            if ((old >> 13) == (tag >> 13)) { atomicMax(&slots[h], packed); break; }
            h = (h + 1) & HMASK;
        }
    }
    __syncthreads();

    // ---- Phase 3: winning edges accumulate YV[i] += adm * V[j] in LDS ----
    for (int e = tid; e < EDGES_PER_B; e += NTHREADS) {
        int m = b * EDGES_PER_B + e;
        int i = ei[m] % N_BUSES;
        int j = ei[TOTAL_EDGES + m] % N_BUSES;
        int key = i * N_BUSES + j;
        ull tag = (ull)(unsigned)(key + 1) << 13;
        unsigned h = hash_key(key);
        ull s;
        while (((s = slots[h]) >> 13) != (tag >> 13)) h = (h + 1) & HMASK;
        if ((int)(s & 0x1FFFULL) != e) continue;   // a later duplicate overwrote this edge
        float2 a = ((const float2*)ea)[m];
        float2 v = ((const float2*)outputs)[b * N_BUSES + j];
        atomicAdd(&yv_sh[2 * i],     a.x * v.x - a.y * v.y);
        atomicAdd(&yv_sh[2 * i + 1], a.x * v.y + a.y * v.x);
    }
    __syncthreads();

    // ---- Phase 4: per-bus loss terms + block reduction ----
    double t0 = 0.0, t1 = 0.0, t2 = 0.0, t3 = 0.0, t4 = 0.0;
    for (int i = tid; i < N_BUSES; i += NTHREADS) {
        int idx = b * N_BUSES + i;
        const float2* row2 = (const float2*)(x + (size_t)idx * 6);
        float2 r0 = row2[0], r1 = row2[1], r2 = row2[2];
        float sre = r0.x, sim = r0.y, Vm = r1.x;
        float bt0 = r1.y, bt1 = r2.x, bt2 = r2.y;
        float2 v = ((const float2*)outputs)[idx];
        float yvr = yv_sh[2 * i], yvi = yv_sh[2 * i + 1];
        // Spred = V * conj(YV)
        float spr = v.x * yvr + v.y * yvi;
        float spi = v.y * yvr - v.x * yvi;
        // |1/S| with exact-zero fallback to 1/S_mean
        float ir, ii;
        if (sre != 0.0f || sim != 0.0f) {
            float den = sre * sre + sim * sim;
            ir = sre / den; ii = -sim / den;
        } else {
            float mr = bst[0], mi = bst[1];
            float den = mr * mr + mi * mi;
            ir = mr / den; ii = -mi / den;
        }
        float sinv_norm = sqrtf(ir * ir + ii * ii);
        float cr = spr - sre, ci = spi - sim;
        t0 += (double)(sinv_norm * ((cr * cr - ci * ci) * bt0 + (cr * cr) * bt1));
        t1 += (double)(sinv_norm * (2.0f * cr * ci * bt0));
        float vminv = (Vm != 0.0f) ? (1.0f / Vm) : (1.0f / bst[2]);
        float vmag = sqrtf(v.x * v.x + v.y * v.y);
        t2 += (double)(fabsf(vmag * (bt1 + bt2) - Vm) * vminv);
        t3 += (double)(fabsf(v.y * bt2) * vminv);
        float2 l = ((const float2*)labels)[idx];
        float e0 = v.x - l.x, e1 = v.y - l.y;
        t4 += (double)(e0 * e0 + e1 * e1);
    }
    for (int off = 32; off > 0; off >>= 1) {
        t0 += __shfl_down(t0, off, 64);
        t1 += __shfl_down(t1, off, 64);
        t2 += __shfl_down(t2, off, 64);
        t3 += __shfl_down(t3, off, 64);
        t4 += __shfl_down(t4, off, 64);
    }
    __syncthreads();   // red[] reuse: ensure phase-1 consumers done
    if (lane == 0) {
        red[0][wave] = t0; red[1][wave] = t1; red[2][wave] = t2;
        red[3][wave] = t3; red[4][wave] = t4;
    }
    __syncthreads();
    if (tid == 0) {
        double a0 = 0, a1 = 0, a2 = 0, a3 = 0, a4 = 0;
        for (int w = 0; w < NTHREADS / 64; w++) {
            a0 += red[0][w]; a1 += red[1][w]; a2 += red[2][w];
            a3 += red[3][w]; a4 += red[4][w];
        }
        part[b * 5 + 0] = a0; part[b * 5 + 1] = a1; part[b * 5 + 2] = a2;
        part[b * 5 + 3] = a3; part[b * 5 + 4] = a4;
    }
}

__global__ void finalize(const double* __restrict__ part, float* __restrict__ out,
                         int out_size) {
    int lane = threadIdx.x & 63;
    double v0 = 0, v1 = 0, v2 = 0, v3 = 0, v4 = 0;
    if (lane < BATCH) {
        v0 = part[lane * 5 + 0]; v1 = part[lane * 5 + 1]; v2 = part[lane * 5 + 2];
        v3 = part[lane * 5 + 3]; v4 = part[lane * 5 + 4];
    }
    for (int off = 32; off > 0; off >>= 1) {
        v0 += __shfl_down(v0, off, 64);
        v1 += __shfl_down(v1, off, 64);
        v2 += __shfl_down(v2, off, 64);
        v3 += __shfl_down(v3, off, 64);
        v4 += __shfl_down(v4, off, 64);
    }
    if (lane == 0) {
        double inv = 1.0 / (double)TOTAL_BUSES;
        double d1re = v0 * inv, d1im = v1 * inv;
        double d2 = v2 * inv, d3 = v3 * inv;
        double mse = v4 / (2.0 * (double)TOTAL_BUSES);
        double phre = d1re + d2 + d3, phim = d1im;
        double lre = mse + 0.1 * phre, lim = 0.1 * phim;
        if (out_size == 8) {
            out[0] = (float)lre;  out[1] = (float)lim;
            out[2] = (float)phre; out[3] = (float)phim;
            out[4] = (float)d1re; out[5] = (float)d1im;
            out[6] = (float)d2;   out[7] = (float)d3;
        } else {
            float vals[5] = {(float)lre, (float)phre, (float)d1re, (float)d2, (float)d3};
            int n = out_size < 5 ? out_size : 5;
            for (int k = 0; k < n; k++) out[k] = vals[k];
            for (int k = 5; k < out_size && k < 64; k++) out[k] = 0.0f;
        }
    }
}

extern "C" void kernel_launch(void* const* d_in, const int* in_sizes, int n_in,
                              void* d_out, int out_size, void* d_ws, size_t ws_size,
                              hipStream_t stream) {
    const float* x       = (const float*)d_in[0];
    const float* ea      = (const float*)d_in[1];
    const int*   ei      = (const int*)d_in[2];
    const float* outputs = (const float*)d_in[3];
    const float* labels  = (const float*)d_in[4];
    double* part = (double*)d_ws;   // 32 * 5 doubles

    fused_image<<<BATCH, NTHREADS, 0, stream>>>(x, ea, ei, outputs, labels, part);
    finalize<<<1, 64, 0, stream>>>(part, (float*)d_out, out_size);
}

// Round 4
// 97.853 us; speedup vs baseline: 1.7388x; 1.4035x over previous
//
#include <hip/hip_runtime.h>

typedef unsigned long long ull;

// Problem constants (from reference)
#define N_BUSES     2000
#define BATCH       32
#define EDGES_PER_B 6000
#define TOTAL_BUSES (BATCH * N_BUSES)     // 64000
#define TOTAL_EDGES (BATCH * EDGES_PER_B) // 192000

#define SPLIT   16                        // blocks per image (bus-range partition)
#define BUS_PER (N_BUSES / SPLIT)         // 125 buses per block
#define TPB     512
#define NBLOCKS (BATCH * SPLIT)           // 512

// Per-block LDS hash: slot = ((key+1) << 13) | local_edge_id, 0 = empty.
// key = i*N_BUSES + j < 4e6 < 2^22; local edge id < 6000 < 2^13.
// Expected keys/block ~375 (sd ~19); 1024 slots => load ~0.43 worst-case-safe.
#define HBITS 10
#define HSIZE (1 << HBITS)
#define HMASK (HSIZE - 1)

__device__ __forceinline__ unsigned hash_key(int key) {
    return ((unsigned)key * 2654435761u) >> (32 - HBITS);
}

__global__ __launch_bounds__(TPB)
void fused_split(const float* __restrict__ x, const float* __restrict__ ea,
                 const int* __restrict__ ei, const float* __restrict__ outputs,
                 const float* __restrict__ labels, double* __restrict__ part) {
    __shared__ ull slots[HSIZE];           // 8 KB
    __shared__ float yv_sh[2 * BUS_PER];   // 1 KB
    __shared__ double red[5][TPB / 64];
    __shared__ float bst[3];               // S_mean re/im, Vm_mean (whole image)

    const int blk = blockIdx.x;
    const int b = blk / SPLIT;             // image
    const int p = blk % SPLIT;             // bus-range part
    const int r0 = p * BUS_PER;
    const int tid = threadIdx.x;
    const int wave = tid >> 6, lane = tid & 63;

    // ---- Phase 0: zero LDS ----
    for (int k = tid; k < HSIZE; k += TPB) slots[k] = 0ULL;
    for (int k = tid; k < 2 * BUS_PER; k += TPB) yv_sh[k] = 0.0f;

    // ---- Phase 1: whole-image means of S (complex) and Vm (zero-fallback) ----
    {
        double sre = 0.0, sim = 0.0, svm = 0.0;
        for (int i = tid; i < N_BUSES; i += TPB) {
            const float* row = x + (size_t)(b * N_BUSES + i) * 6;
            sre += (double)row[0];
            sim += (double)row[1];
            svm += (double)row[2];
        }
        for (int off = 32; off > 0; off >>= 1) {
            sre += __shfl_down(sre, off, 64);
            sim += __shfl_down(sim, off, 64);
            svm += __shfl_down(svm, off, 64);
        }
        if (lane == 0) { red[0][wave] = sre; red[1][wave] = sim; red[2][wave] = svm; }
        __syncthreads();   // also covers phase-0 zeroing
        if (tid == 0) {
            double a = 0, c = 0, d = 0;
            for (int w = 0; w < TPB / 64; w++) { a += red[0][w]; c += red[1][w]; d += red[2][w]; }
            bst[0] = (float)(a / N_BUSES);
            bst[1] = (float)(c / N_BUSES);
            bst[2] = (float)(d / N_BUSES);
        }
        __syncthreads();
    }

    // ---- Phase 2: scan image edges, filter to our bus range, LDS-hash insert
    // (last-write-wins per (i,j): winner = max local edge id). Duplicates share
    // i, so they always land in the same block — dedup is block-local.
    for (int e = tid; e < EDGES_PER_B; e += TPB) {
        int m = b * EDGES_PER_B + e;
        int i = ei[m] % N_BUSES;
        if (i < r0 || i >= r0 + BUS_PER) continue;
        int j = ei[TOTAL_EDGES + m] % N_BUSES;
        int key = i * N_BUSES + j;
        ull tag = (ull)(unsigned)(key + 1) << 13;
        ull packed = tag | (unsigned)e;
        unsigned h = hash_key(key);
        while (true) {
            ull old = atomicCAS(&slots[h], 0ULL, packed);
            if (old == 0ULL) break;
            if ((old >> 13) == (ull)(unsigned)(key + 1)) { atomicMax(&slots[h], packed); break; }
            h = (h + 1) & HMASK;
        }
    }
    __syncthreads();

    // ---- Phase 3: winning edges accumulate YV[i] += adm * V[j] in LDS ----
    for (int e = tid; e < EDGES_PER_B; e += TPB) {
        int m = b * EDGES_PER_B + e;
        int i = ei[m] % N_BUSES;
        if (i < r0 || i >= r0 + BUS_PER) continue;
        int j = ei[TOTAL_EDGES + m] % N_BUSES;
        int key = i * N_BUSES + j;
        unsigned h = hash_key(key);
        ull s;
        while (((s = slots[h]) >> 13) != (ull)(unsigned)(key + 1)) h = (h + 1) & HMASK;
        if ((int)(s & 0x1FFFULL) != e) continue;   // a later duplicate overwrote this edge
        float2 a = ((const float2*)ea)[m];
        float2 v = ((const float2*)outputs)[b * N_BUSES + j];
        int il = i - r0;
        atomicAdd(&yv_sh[2 * il],     a.x * v.x - a.y * v.y);
        atomicAdd(&yv_sh[2 * il + 1], a.x * v.y + a.y * v.x);
    }
    __syncthreads();

    // ---- Phase 4: per-bus loss terms over our 125-bus range + reduction ----
    double t0 = 0.0, t1 = 0.0, t2 = 0.0, t3 = 0.0, t4 = 0.0;
    for (int il = tid; il < BUS_PER; il += TPB) {
        int idx = b * N_BUSES + r0 + il;
        const float2* row2 = (const float2*)(x + (size_t)idx * 6);
        float2 q0 = row2[0], q1 = row2[1], q2 = row2[2];
        float sre = q0.x, sim = q0.y, Vm = q1.x;
        float bt0 = q1.y, bt1 = q2.x, bt2 = q2.y;
        float2 v = ((const float2*)outputs)[idx];
        float yvr = yv_sh[2 * il], yvi = yv_sh[2 * il + 1];
        // Spred = V * conj(YV)
        float spr = v.x * yvr + v.y * yvi;
        float spi = v.y * yvr - v.x * yvi;
        // |1/S| with exact-zero fallback to 1/S_mean
        float ir, ii;
        if (sre != 0.0f || sim != 0.0f) {
            float den = sre * sre + sim * sim;
            ir = sre / den; ii = -sim / den;
        } else {
            float mr = bst[0], mi = bst[1];
            float den = mr * mr + mi * mi;
            ir = mr / den; ii = -mi / den;
        }
        float sinv_norm = sqrtf(ir * ir + ii * ii);
        float cr = spr - sre, ci = spi - sim;
        t0 += (double)(sinv_norm * ((cr * cr - ci * ci) * bt0 + (cr * cr) * bt1));
        t1 += (double)(sinv_norm * (2.0f * cr * ci * bt0));
        float vminv = (Vm != 0.0f) ? (1.0f / Vm) : (1.0f / bst[2]);
        float vmag = sqrtf(v.x * v.x + v.y * v.y);
        t2 += (double)(fabsf(vmag * (bt1 + bt2) - Vm) * vminv);
        t3 += (double)(fabsf(v.y * bt2) * vminv);
        float2 l = ((const float2*)labels)[idx];
        float e0 = v.x - l.x, e1 = v.y - l.y;
        t4 += (double)(e0 * e0 + e1 * e1);
    }
    for (int off = 32; off > 0; off >>= 1) {
        t0 += __shfl_down(t0, off, 64);
        t1 += __shfl_down(t1, off, 64);
        t2 += __shfl_down(t2, off, 64);
        t3 += __shfl_down(t3, off, 64);
        t4 += __shfl_down(t4, off, 64);
    }
    __syncthreads();   // red[] reuse after phase 1
    if (lane == 0) {
        red[0][wave] = t0; red[1][wave] = t1; red[2][wave] = t2;
        red[3][wave] = t3; red[4][wave] = t4;
    }
    __syncthreads();
    if (tid == 0) {
        double a0 = 0, a1 = 0, a2 = 0, a3 = 0, a4 = 0;
        for (int w = 0; w < TPB / 64; w++) {
            a0 += red[0][w]; a1 += red[1][w]; a2 += red[2][w];
            a3 += red[3][w]; a4 += red[4][w];
        }
        part[blk * 5 + 0] = a0; part[blk * 5 + 1] = a1; part[blk * 5 + 2] = a2;
        part[blk * 5 + 3] = a3; part[blk * 5 + 4] = a4;
    }
}

__global__ __launch_bounds__(TPB)
void finalize(const double* __restrict__ part, float* __restrict__ out, int out_size) {
    int tid = threadIdx.x;
    int wave = tid >> 6, lane = tid & 63;
    double v0 = part[tid * 5 + 0], v1 = part[tid * 5 + 1], v2 = part[tid * 5 + 2];
    double v3 = part[tid * 5 + 3], v4 = part[tid * 5 + 4];
    for (int off = 32; off > 0; off >>= 1) {
        v0 += __shfl_down(v0, off, 64);
        v1 += __shfl_down(v1, off, 64);
        v2 += __shfl_down(v2, off, 64);
        v3 += __shfl_down(v3, off, 64);
        v4 += __shfl_down(v4, off, 64);
    }
    __shared__ double sh[5][TPB / 64];
    if (lane == 0) {
        sh[0][wave] = v0; sh[1][wave] = v1; sh[2][wave] = v2;
        sh[3][wave] = v3; sh[4][wave] = v4;
    }
    __syncthreads();
    if (tid == 0) {
        double a0 = 0, a1 = 0, a2 = 0, a3 = 0, a4 = 0;
        for (int w = 0; w < TPB / 64; w++) {
            a0 += sh[0][w]; a1 += sh[1][w]; a2 += sh[2][w];
            a3 += sh[3][w]; a4 += sh[4][w];
        }
        double inv = 1.0 / (double)TOTAL_BUSES;
        double d1re = a0 * inv, d1im = a1 * inv;
        double d2 = a2 * inv, d3 = a3 * inv;
        double mse = a4 / (2.0 * (double)TOTAL_BUSES);
        double phre = d1re + d2 + d3, phim = d1im;
        double lre = mse + 0.1 * phre, lim = 0.1 * phim;
        if (out_size == 8) {
            out[0] = (float)lre;  out[1] = (float)lim;
            out[2] = (float)phre; out[3] = (float)phim;
            out[4] = (float)d1re; out[5] = (float)d1im;
            out[6] = (float)d2;   out[7] = (float)d3;
        } else {
            float vals[5] = {(float)lre, (float)phre, (float)d1re, (float)d2, (float)d3};
            int n = out_size < 5 ? out_size : 5;
            for (int k = 0; k < n; k++) out[k] = vals[k];
            for (int k = 5; k < out_size && k < 64; k++) out[k] = 0.0f;
        }
    }
}

extern "C" void kernel_launch(void* const* d_in, const int* in_sizes, int n_in,
                              void* d_out, int out_size, void* d_ws, size_t ws_size,
                              hipStream_t stream) {
    const float* x       = (const float*)d_in[0];
    const float* ea      = (const float*)d_in[1];
    const int*   ei      = (const int*)d_in[2];
    const float* outputs = (const float*)d_in[3];
    const float* labels  = (const float*)d_in[4];
    double* part = (double*)d_ws;   // NBLOCKS * 5 doubles = 20 KB

    fused_split<<<NBLOCKS, TPB, 0, stream>>>(x, ea, ei, outputs, labels, part);
    finalize<<<1, TPB, 0, stream>>>(part, (float*)d_out, out_size);
}

// Round 5
// 84.302 us; speedup vs baseline: 2.0183x; 1.1607x over previous
//
#include <hip/hip_runtime.h>

typedef unsigned long long ull;

// Problem constants (from reference)
#define N_BUSES     2000
#define BATCH       32
#define EDGES_PER_B 6000
#define TOTAL_BUSES (BATCH * N_BUSES)     // 64000
#define TOTAL_EDGES (BATCH * EDGES_PER_B) // 192000

#define SPLIT   16                        // blocks per image (bus-range partition)
#define BUS_PER (N_BUSES / SPLIT)         // 125 buses per block
#define TPB     1024
#define NBLOCKS (BATCH * SPLIT)           // 512
#define EPT     6                         // ceil(6000/1024) edges per thread

// Per-block LDS hash: slot = ((key+1) << 13) | local_edge_id, 0 = empty.
// key = i*N_BUSES + j < 4e6 < 2^22; local edge id < 6000 < 2^13.
// ~375 keys/block (sd ~19) in 1024 slots => load <=0.5.
#define HBITS 10
#define HSIZE (1 << HBITS)
#define HMASK (HSIZE - 1)

__device__ __forceinline__ unsigned hash_key(int key) {
    return ((unsigned)key * 2654435761u) >> (32 - HBITS);
}

__global__ __launch_bounds__(TPB)
void fused_split(const float* __restrict__ x, const float* __restrict__ ea,
                 const int* __restrict__ ei, const float* __restrict__ outputs,
                 const float* __restrict__ labels, double* __restrict__ part) {
    __shared__ ull slots[HSIZE];           // 8 KB
    __shared__ float yv_sh[2 * BUS_PER];   // 1 KB
    __shared__ double red[5][TPB / 64];
    __shared__ double red2[3][TPB / 64];
    __shared__ float bst[3];
    __shared__ int pend[64];
    __shared__ int npend;

    const int blk = blockIdx.x;
    const int b = blk / SPLIT;             // image
    const int p = blk % SPLIT;             // bus-range part
    const int r0 = p * BUS_PER;
    const int tid = threadIdx.x;
    const int wave = tid >> 6, lane = tid & 63;

    // ---- Prefetch this thread's edge endpoints (independent coalesced loads,
    // issued before the barrier so they overlap LDS zeroing) ----
    int iv[EPT], jv[EPT];
#pragma unroll
    for (int k = 0; k < EPT; k++) {
        int e = tid + k * TPB;
        if (e < EDGES_PER_B) {
            iv[k] = ei[b * EDGES_PER_B + e];
            jv[k] = ei[TOTAL_EDGES + b * EDGES_PER_B + e];
        } else { iv[k] = -1; jv[k] = 0; }
    }

    // ---- Phase 0: zero LDS ----
    slots[tid] = 0ULL;                     // HSIZE == TPB
    if (tid < 2 * BUS_PER) yv_sh[tid] = 0.0f;
    if (tid == 0) npend = 0;
    __syncthreads();

    // ---- Phase 1: single-pass dedup insert + compensated YV accumulation.
    // numpy fancy-assign: last write per (i,j) wins = max local edge id.
    // Duplicates share i => always same block. When we depose a previous
    // winner, subtract its contribution (same key => same j => same V[j]).
#pragma unroll
    for (int k = 0; k < EPT; k++) {
        int e = tid + k * TPB;
        if (iv[k] < 0) continue;
        int i = iv[k] % N_BUSES;
        if (i < r0 || i >= r0 + BUS_PER) continue;
        int j = jv[k] % N_BUSES;
        int key = i * N_BUSES + j;
        ull tag = (ull)(unsigned)(key + 1) << 13;
        ull packed = tag | (unsigned)e;
        unsigned h = hash_key(key);
        int deposed = -1;
        bool we_add = false;
        while (true) {
            ull old = atomicCAS(&slots[h], 0ULL, packed);
            if (old == 0ULL) { we_add = true; break; }
            if ((old >> 13) == (ull)(unsigned)(key + 1)) {
                ull prev = atomicMax(&slots[h], packed);
                if (prev < packed) { we_add = true; deposed = (int)(prev & 0x1FFFULL); }
                break;
            }
            h = (h + 1) & HMASK;
        }
        if (we_add) {
            float2 v = ((const float2*)outputs)[b * N_BUSES + j];
            float2 a = ((const float2*)ea)[b * EDGES_PER_B + e];
            float addr = a.x * v.x - a.y * v.y;
            float addi = a.x * v.y + a.y * v.x;
            if (deposed >= 0) {   // rare (~5 per image): undo deposed winner
                float2 ap = ((const float2*)ea)[b * EDGES_PER_B + deposed];
                addr -= ap.x * v.x - ap.y * v.y;
                addi -= ap.x * v.y + ap.y * v.x;
            }
            int il = i - r0;
            atomicAdd(&yv_sh[2 * il],     addr);
            atomicAdd(&yv_sh[2 * il + 1], addi);
        }
    }
    __syncthreads();

    // ---- Phase 2: per-bus loss terms over our 125-bus range ----
    double t0 = 0.0, t1 = 0.0, t2 = 0.0, t3 = 0.0, t4 = 0.0;
    if (tid < BUS_PER) {
        int il = tid;
        int idx = b * N_BUSES + r0 + il;
        const float2* row2 = (const float2*)(x + (size_t)idx * 6);
        float2 q0 = row2[0], q1 = row2[1], q2 = row2[2];
        float sre = q0.x, sim = q0.y, Vm = q1.x;
        float bt0 = q1.y, bt1 = q2.x, bt2 = q2.y;
        if ((sre == 0.0f && sim == 0.0f) || Vm == 0.0f) {
            // exact-zero fallback needs image means — defer (rare/never)
            int pp = atomicAdd(&npend, 1);
            if (pp < 64) pend[pp] = il;
        } else {
            float2 v = ((const float2*)outputs)[idx];
            float yvr = yv_sh[2 * il], yvi = yv_sh[2 * il + 1];
            float spr = v.x * yvr + v.y * yvi;     // Spred = V * conj(YV)
            float spi = v.y * yvr - v.x * yvi;
            float den = sre * sre + sim * sim;
            float ir = sre / den, ii = -sim / den;
            float sinv_norm = sqrtf(ir * ir + ii * ii);
            float cr = spr - sre, ci = spi - sim;
            t0 = (double)(sinv_norm * ((cr * cr - ci * ci) * bt0 + (cr * cr) * bt1));
            t1 = (double)(sinv_norm * (2.0f * cr * ci * bt0));
            float vminv = 1.0f / Vm;
            float vmag = sqrtf(v.x * v.x + v.y * v.y);
            t2 = (double)(fabsf(vmag * (bt1 + bt2) - Vm) * vminv);
            t3 = (double)(fabsf(v.y * bt2) * vminv);
            float2 l = ((const float2*)labels)[idx];
            float e0 = v.x - l.x, e1 = v.y - l.y;
            t4 = (double)(e0 * e0 + e1 * e1);
        }
    }
    for (int off = 32; off > 0; off >>= 1) {
        t0 += __shfl_down(t0, off, 64);
        t1 += __shfl_down(t1, off, 64);
        t2 += __shfl_down(t2, off, 64);
        t3 += __shfl_down(t3, off, 64);
        t4 += __shfl_down(t4, off, 64);
    }
    if (lane == 0) {
        red[0][wave] = t0; red[1][wave] = t1; red[2][wave] = t2;
        red[3][wave] = t3; red[4][wave] = t4;
    }
    __syncthreads();

    double a0 = 0, a1 = 0, a2 = 0, a3 = 0, a4 = 0;
    if (tid == 0) {
        for (int w = 0; w < TPB / 64; w++) {
            a0 += red[0][w]; a1 += red[1][w]; a2 += red[2][w];
            a3 += red[3][w]; a4 += red[4][w];
        }
    }

    // ---- Rare path: some bus had exact-zero S or Vm -> compute image means
    // (bit-faithful to reference) and process pending buses serially.
    if (npend > 0) {
        double sre = 0.0, sim = 0.0, svm = 0.0;
        for (int i = tid; i < N_BUSES; i += TPB) {
            const float* row = x + (size_t)(b * N_BUSES + i) * 6;
            sre += (double)row[0];
            sim += (double)row[1];
            svm += (double)row[2];
        }
        for (int off = 32; off > 0; off >>= 1) {
            sre += __shfl_down(sre, off, 64);
            sim += __shfl_down(sim, off, 64);
            svm += __shfl_down(svm, off, 64);
        }
        if (lane == 0) { red2[0][wave] = sre; red2[1][wave] = sim; red2[2][wave] = svm; }
        __syncthreads();
        if (tid == 0) {
            double sa = 0, sb = 0, sc = 0;
            for (int w = 0; w < TPB / 64; w++) { sa += red2[0][w]; sb += red2[1][w]; sc += red2[2][w]; }
            bst[0] = (float)(sa / N_BUSES);
            bst[1] = (float)(sb / N_BUSES);
            bst[2] = (float)(sc / N_BUSES);
        }
        __syncthreads();
        if (tid == 0) {
            int np = npend < 64 ? npend : 64;
            for (int q = 0; q < np; q++) {
                int il = pend[q];
                int idx = b * N_BUSES + r0 + il;
                const float2* row2 = (const float2*)(x + (size_t)idx * 6);
                float2 q0 = row2[0], q1 = row2[1], q2 = row2[2];
                float sr = q0.x, si = q0.y, Vm = q1.x;
                float bt0 = q1.y, bt1 = q2.x, bt2 = q2.y;
                float2 v = ((const float2*)outputs)[idx];
                float yvr = yv_sh[2 * il], yvi = yv_sh[2 * il + 1];
                float spr = v.x * yvr + v.y * yvi;
                float spi = v.y * yvr - v.x * yvi;
                float ir, ii;
                if (sr != 0.0f || si != 0.0f) {
                    float den = sr * sr + si * si;
                    ir = sr / den; ii = -si / den;
                } else {
                    float mr = bst[0], mi = bst[1];
                    float den = mr * mr + mi * mi;
                    ir = mr / den; ii = -mi / den;
                }
                float sinv_norm = sqrtf(ir * ir + ii * ii);
                float cr = spr - sr, ci = spi - si;
                a0 += (double)(sinv_norm * ((cr * cr - ci * ci) * bt0 + (cr * cr) * bt1));
                a1 += (double)(sinv_norm * (2.0f * cr * ci * bt0));
                float vminv = (Vm != 0.0f) ? (1.0f / Vm) : (1.0f / bst[2]);
                float vmag = sqrtf(v.x * v.x + v.y * v.y);
                a2 += (double)(fabsf(vmag * (bt1 + bt2) - Vm) * vminv);
                a3 += (double)(fabsf(v.y * bt2) * vminv);
                float2 l = ((const float2*)labels)[idx];
                float e0 = v.x - l.x, e1 = v.y - l.y;
                a4 += (double)(e0 * e0 + e1 * e1);
            }
        }
    }

    if (tid == 0) {
        part[blk * 5 + 0] = a0; part[blk * 5 + 1] = a1; part[blk * 5 + 2] = a2;
        part[blk * 5 + 3] = a3; part[blk * 5 + 4] = a4;
    }
}

__global__ __launch_bounds__(512)
void finalize(const double* __restrict__ part, float* __restrict__ out, int out_size) {
    int tid = threadIdx.x;
    int wave = tid >> 6, lane = tid & 63;
    double v0 = part[tid * 5 + 0], v1 = part[tid * 5 + 1], v2 = part[tid * 5 + 2];
    double v3 = part[tid * 5 + 3], v4 = part[tid * 5 + 4];
    for (int off = 32; off > 0; off >>= 1) {
        v0 += __shfl_down(v0, off, 64);
        v1 += __shfl_down(v1, off, 64);
        v2 += __shfl_down(v2, off, 64);
        v3 += __shfl_down(v3, off, 64);
        v4 += __shfl_down(v4, off, 64);
    }
    __shared__ double sh[5][8];
    if (lane == 0) {
        sh[0][wave] = v0; sh[1][wave] = v1; sh[2][wave] = v2;
        sh[3][wave] = v3; sh[4][wave] = v4;
    }
    __syncthreads();
    if (tid == 0) {
        double a0 = 0, a1 = 0, a2 = 0, a3 = 0, a4 = 0;
        for (int w = 0; w < 8; w++) {
            a0 += sh[0][w]; a1 += sh[1][w]; a2 += sh[2][w];
            a3 += sh[3][w]; a4 += sh[4][w];
        }
        double inv = 1.0 / (double)TOTAL_BUSES;
        double d1re = a0 * inv, d1im = a1 * inv;
        double d2 = a2 * inv, d3 = a3 * inv;
        double mse = a4 / (2.0 * (double)TOTAL_BUSES);
        double phre = d1re + d2 + d3, phim = d1im;
        double lre = mse + 0.1 * phre, lim = 0.1 * phim;
        if (out_size == 8) {
            out[0] = (float)lre;  out[1] = (float)lim;
            out[2] = (float)phre; out[3] = (float)phim;
            out[4] = (float)d1re; out[5] = (float)d1im;
            out[6] = (float)d2;   out[7] = (float)d3;
        } else {
            float vals[5] = {(float)lre, (float)phre, (float)d1re, (float)d2, (float)d3};
            int n = out_size < 5 ? out_size : 5;
            for (int k = 0; k < n; k++) out[k] = vals[k];
            for (int k = 5; k < out_size && k < 64; k++) out[k] = 0.0f;
        }
    }
}

extern "C" void kernel_launch(void* const* d_in, const int* in_sizes, int n_in,
                              void* d_out, int out_size, void* d_ws, size_t ws_size,
                              hipStream_t stream) {
    const float* x       = (const float*)d_in[0];
    const float* ea      = (const float*)d_in[1];
    const int*   ei      = (const int*)d_in[2];
    const float* outputs = (const float*)d_in[3];
    const float* labels  = (const float*)d_in[4];
    double* part = (double*)d_ws;   // NBLOCKS * 5 doubles = 20 KB

    fused_split<<<NBLOCKS, TPB, 0, stream>>>(x, ea, ei, outputs, labels, part);
    finalize<<<1, 512, 0, stream>>>(part, (float*)d_out, out_size);
}

// Round 6
// 83.615 us; speedup vs baseline: 2.0349x; 1.0082x over previous
//
#include <hip/hip_runtime.h>

typedef unsigned long long ull;

// Problem constants (from reference)
#define N_BUSES     2000
#define BATCH       32
#define EDGES_PER_B 6000
#define TOTAL_BUSES (BATCH * N_BUSES)     // 64000
#define TOTAL_EDGES (BATCH * EDGES_PER_B) // 192000

#define SPLIT   8                         // blocks per image (bus-range partition)
#define BUS_PER (N_BUSES / SPLIT)         // 250 buses per block
#define TPB     1024
#define NBLOCKS (BATCH * SPLIT)           // 256 = one resident round on 256 CUs
#define EPT     6                         // ceil(6000/1024) edges per thread

// Per-block LDS hash: slot = ((key+1) << 13) | local_edge_id, 0 = empty.
// key = i*N_BUSES + j < 4e6 < 2^22; local edge id < 6000 < 2^13.
// ~750 keys/block in 2048 slots => load ~0.37.
#define HBITS 11
#define HSIZE (1 << HBITS)
#define HMASK (HSIZE - 1)

__device__ __forceinline__ unsigned hash_key(int key) {
    return ((unsigned)key * 2654435761u) >> (32 - HBITS);
}

__global__ __launch_bounds__(TPB)
void fused_split(const float* __restrict__ x, const float* __restrict__ ea,
                 const int* __restrict__ ei, const float* __restrict__ outputs,
                 const float* __restrict__ labels, double* __restrict__ part) {
    __shared__ ull slots[HSIZE];           // 16 KB
    __shared__ float yv_sh[2 * BUS_PER];   // 2 KB
    __shared__ double red[5][TPB / 64];
    __shared__ double red2[3][TPB / 64];
    __shared__ float bst[3];
    __shared__ int pend[64];
    __shared__ int npend;

    const int blk = blockIdx.x;
    const int b = blk / SPLIT;             // image
    const int p = blk % SPLIT;             // bus-range part
    const int r0 = p * BUS_PER;
    const int tid = threadIdx.x;
    const int wave = tid >> 6, lane = tid & 63;

    // ---- Prefetch A: phase-2 operands (independent of everything below;
    // in flight during LDS zeroing and the whole edge phase) ----
    float2 q0, q1, q2, vP, lP;
    const int idxP = b * N_BUSES + r0 + tid;   // valid when tid < BUS_PER
    if (tid < BUS_PER) {
        const float2* row2 = (const float2*)(x + (size_t)idxP * 6);
        q0 = row2[0]; q1 = row2[1]; q2 = row2[2];
        vP = ((const float2*)outputs)[idxP];
        lP = ((const float2*)labels)[idxP];
    }

    // ---- Prefetch B: this thread's edge endpoints (coalesced), then the
    // ea / V[j] operands for in-range edges (independent of the hash) ----
    int iv[EPT], jv[EPT];
#pragma unroll
    for (int k = 0; k < EPT; k++) {
        int e = tid + k * TPB;
        if (e < EDGES_PER_B) {
            iv[k] = ei[b * EDGES_PER_B + e] % N_BUSES;
            jv[k] = ei[TOTAL_EDGES + b * EDGES_PER_B + e] % N_BUSES;
        } else { iv[k] = -1; jv[k] = 0; }
    }
    float2 av[EPT], vv[EPT];
    bool inr[EPT];
#pragma unroll
    for (int k = 0; k < EPT; k++) {
        int i = iv[k];
        inr[k] = (i >= r0) && (i < r0 + BUS_PER);
        if (inr[k]) {
            av[k] = ((const float2*)ea)[b * EDGES_PER_B + tid + k * TPB];
            vv[k] = ((const float2*)outputs)[b * N_BUSES + jv[k]];
        }
    }

    // ---- Phase 0: zero LDS ----
    slots[tid] = 0ULL;
    slots[tid + TPB] = 0ULL;               // HSIZE == 2*TPB
    if (tid < 2 * BUS_PER) yv_sh[tid] = 0.0f;
    if (tid == 0) npend = 0;
    __syncthreads();

    // ---- Phase 1: single-pass dedup insert + compensated YV accumulation.
    // numpy fancy-assign: last write per (i,j) wins = max local edge id.
    // Duplicates share i => always same block. When we depose a previous
    // winner, subtract its contribution (same key => same j => same V[j]).
#pragma unroll
    for (int k = 0; k < EPT; k++) {
        if (!inr[k]) continue;
        int e = tid + k * TPB;
        int i = iv[k], j = jv[k];
        int key = i * N_BUSES + j;
        ull tag = (ull)(unsigned)(key + 1) << 13;
        ull packed = tag | (unsigned)e;
        unsigned h = hash_key(key);
        int deposed = -1;
        bool we_add = false;
        while (true) {
            ull old = atomicCAS(&slots[h], 0ULL, packed);
            if (old == 0ULL) { we_add = true; break; }
            if ((old >> 13) == (ull)(unsigned)(key + 1)) {
                ull prev = atomicMax(&slots[h], packed);
                if (prev < packed) { we_add = true; deposed = (int)(prev & 0x1FFFULL); }
                break;
            }
            h = (h + 1) & HMASK;
        }
        if (we_add) {
            float2 a = av[k], v = vv[k];
            float addr = a.x * v.x - a.y * v.y;
            float addi = a.x * v.y + a.y * v.x;
            if (deposed >= 0) {   // rare (~5 per image): undo deposed winner
                float2 ap = ((const float2*)ea)[b * EDGES_PER_B + deposed];
                addr -= ap.x * v.x - ap.y * v.y;
                addi -= ap.x * v.y + ap.y * v.x;
            }
            int il = i - r0;
            atomicAdd(&yv_sh[2 * il],     addr);
            atomicAdd(&yv_sh[2 * il + 1], addi);
        }
    }
    __syncthreads();

    // ---- Phase 2: per-bus loss terms over our 250-bus range ----
    double t0 = 0.0, t1 = 0.0, t2 = 0.0, t3 = 0.0, t4 = 0.0;
    if (tid < BUS_PER) {
        int il = tid;
        float sre = q0.x, sim = q0.y, Vm = q1.x;
        float bt0 = q1.y, bt1 = q2.x, bt2 = q2.y;
        if ((sre == 0.0f && sim == 0.0f) || Vm == 0.0f) {
            // exact-zero fallback needs image means — defer (rare/never)
            int pp = atomicAdd(&npend, 1);
            if (pp < 64) pend[pp] = il;
        } else {
            float yvr = yv_sh[2 * il], yvi = yv_sh[2 * il + 1];
            float spr = vP.x * yvr + vP.y * yvi;   // Spred = V * conj(YV)
            float spi = vP.y * yvr - vP.x * yvi;
            float den = sre * sre + sim * sim;
            float ir = sre / den, ii = -sim / den;
            float sinv_norm = sqrtf(ir * ir + ii * ii);
            float cr = spr - sre, ci = spi - sim;
            t0 = (double)(sinv_norm * ((cr * cr - ci * ci) * bt0 + (cr * cr) * bt1));
            t1 = (double)(sinv_norm * (2.0f * cr * ci * bt0));
            float vminv = 1.0f / Vm;
            float vmag = sqrtf(vP.x * vP.x + vP.y * vP.y);
            t2 = (double)(fabsf(vmag * (bt1 + bt2) - Vm) * vminv);
            t3 = (double)(fabsf(vP.y * bt2) * vminv);
            float e0 = vP.x - lP.x, e1 = vP.y - lP.y;
            t4 = (double)(e0 * e0 + e1 * e1);
        }
    }
    for (int off = 32; off > 0; off >>= 1) {
        t0 += __shfl_down(t0, off, 64);
        t1 += __shfl_down(t1, off, 64);
        t2 += __shfl_down(t2, off, 64);
        t3 += __shfl_down(t3, off, 64);
        t4 += __shfl_down(t4, off, 64);
    }
    if (lane == 0) {
        red[0][wave] = t0; red[1][wave] = t1; red[2][wave] = t2;
        red[3][wave] = t3; red[4][wave] = t4;
    }
    __syncthreads();

    double a0 = 0, a1 = 0, a2 = 0, a3 = 0, a4 = 0;
    if (tid == 0) {
        for (int w = 0; w < TPB / 64; w++) {
            a0 += red[0][w]; a1 += red[1][w]; a2 += red[2][w];
            a3 += red[3][w]; a4 += red[4][w];
        }
    }

    // ---- Rare path: some bus had exact-zero S or Vm -> compute image means
    // (bit-faithful to reference) and process pending buses serially.
    if (npend > 0) {
        double sre = 0.0, sim = 0.0, svm = 0.0;
        for (int i = tid; i < N_BUSES; i += TPB) {
            const float* row = x + (size_t)(b * N_BUSES + i) * 6;
            sre += (double)row[0];
            sim += (double)row[1];
            svm += (double)row[2];
        }
        for (int off = 32; off > 0; off >>= 1) {
            sre += __shfl_down(sre, off, 64);
            sim += __shfl_down(sim, off, 64);
            svm += __shfl_down(svm, off, 64);
        }
        if (lane == 0) { red2[0][wave] = sre; red2[1][wave] = sim; red2[2][wave] = svm; }
        __syncthreads();
        if (tid == 0) {
            double sa = 0, sb = 0, sc = 0;
            for (int w = 0; w < TPB / 64; w++) { sa += red2[0][w]; sb += red2[1][w]; sc += red2[2][w]; }
            bst[0] = (float)(sa / N_BUSES);
            bst[1] = (float)(sb / N_BUSES);
            bst[2] = (float)(sc / N_BUSES);
        }
        __syncthreads();
        if (tid == 0) {
            int np = npend < 64 ? npend : 64;
            for (int q = 0; q < np; q++) {
                int il = pend[q];
                int idx = b * N_BUSES + r0 + il;
                const float2* row2 = (const float2*)(x + (size_t)idx * 6);
                float2 w0 = row2[0], w1 = row2[1], w2 = row2[2];
                float sr = w0.x, si = w0.y, Vm = w1.x;
                float bt0 = w1.y, bt1 = w2.x, bt2 = w2.y;
                float2 v = ((const float2*)outputs)[idx];
                float yvr = yv_sh[2 * il], yvi = yv_sh[2 * il + 1];
                float spr = v.x * yvr + v.y * yvi;
                float spi = v.y * yvr - v.x * yvi;
                float ir, ii;
                if (sr != 0.0f || si != 0.0f) {
                    float den = sr * sr + si * si;
                    ir = sr / den; ii = -si / den;
                } else {
                    float mr = bst[0], mi = bst[1];
                    float den = mr * mr + mi * mi;
                    ir = mr / den; ii = -mi / den;
                }
                float sinv_norm = sqrtf(ir * ir + ii * ii);
                float cr = spr - sr, ci = spi - si;
                a0 += (double)(sinv_norm * ((cr * cr - ci * ci) * bt0 + (cr * cr) * bt1));
                a1 += (double)(sinv_norm * (2.0f * cr * ci * bt0));
                float vminv = (Vm != 0.0f) ? (1.0f / Vm) : (1.0f / bst[2]);
                float vmag = sqrtf(v.x * v.x + v.y * v.y);
                a2 += (double)(fabsf(vmag * (bt1 + bt2) - Vm) * vminv);
                a3 += (double)(fabsf(v.y * bt2) * vminv);
                float2 l = ((const float2*)labels)[idx];
                float e0 = v.x - l.x, e1 = v.y - l.y;
                a4 += (double)(e0 * e0 + e1 * e1);
            }
        }
    }

    if (tid == 0) {
        part[blk * 5 + 0] = a0; part[blk * 5 + 1] = a1; part[blk * 5 + 2] = a2;
        part[blk * 5 + 3] = a3; part[blk * 5 + 4] = a4;
    }
}

__global__ __launch_bounds__(256)
void finalize(const double* __restrict__ part, float* __restrict__ out, int out_size) {
    int tid = threadIdx.x;               // 256 threads, one per block partial
    int wave = tid >> 6, lane = tid & 63;
    double v0 = part[tid * 5 + 0], v1 = part[tid * 5 + 1], v2 = part[tid * 5 + 2];
    double v3 = part[tid * 5 + 3], v4 = part[tid * 5 + 4];
    for (int off = 32; off > 0; off >>= 1) {
        v0 += __shfl_down(v0, off, 64);
        v1 += __shfl_down(v1, off, 64);
        v2 += __shfl_down(v2, off, 64);
        v3 += __shfl_down(v3, off, 64);
        v4 += __shfl_down(v4, off, 64);
    }
    __shared__ double sh[5][4];
    if (lane == 0) {
        sh[0][wave] = v0; sh[1][wave] = v1; sh[2][wave] = v2;
        sh[3][wave] = v3; sh[4][wave] = v4;
    }
    __syncthreads();
    if (tid == 0) {
        double a0 = 0, a1 = 0, a2 = 0, a3 = 0, a4 = 0;
        for (int w = 0; w < 4; w++) {
            a0 += sh[0][w]; a1 += sh[1][w]; a2 += sh[2][w];
            a3 += sh[3][w]; a4 += sh[4][w];
        }
        double inv = 1.0 / (double)TOTAL_BUSES;
        double d1re = a0 * inv, d1im = a1 * inv;
        double d2 = a2 * inv, d3 = a3 * inv;
        double mse = a4 / (2.0 * (double)TOTAL_BUSES);
        double phre = d1re + d2 + d3, phim = d1im;
        double lre = mse + 0.1 * phre, lim = 0.1 * phim;
        if (out_size == 8) {
            out[0] = (float)lre;  out[1] = (float)lim;
            out[2] = (float)phre; out[3] = (float)phim;
            out[4] = (float)d1re; out[5] = (float)d1im;
            out[6] = (float)d2;   out[7] = (float)d3;
        } else {
            float vals[5] = {(float)lre, (float)phre, (float)d1re, (float)d2, (float)d3};
            int n = out_size < 5 ? out_size : 5;
            for (int k = 0; k < n; k++) out[k] = vals[k];
            for (int k = 5; k < out_size && k < 64; k++) out[k] = 0.0f;
        }
    }
}

extern "C" void kernel_launch(void* const* d_in, const int* in_sizes, int n_in,
                              void* d_out, int out_size, void* d_ws, size_t ws_size,
                              hipStream_t stream) {
    const float* x       = (const float*)d_in[0];
    const float* ea      = (const float*)d_in[1];
    const int*   ei      = (const int*)d_in[2];
    const float* outputs = (const float*)d_in[3];
    const float* labels  = (const float*)d_in[4];
    double* part = (double*)d_ws;   // NBLOCKS * 5 doubles = 10 KB

    fused_split<<<NBLOCKS, TPB, 0, stream>>>(x, ea, ei, outputs, labels, part);
    finalize<<<1, 256, 0, stream>>>(part, (float*)d_out, out_size);
}